// Round 1
// baseline (1846.759 us; speedup 1.0000x reference)
//
#include <hip/hip_runtime.h>

#define N_USERS 100000
#define M_ITEMS 50000
#define NNODES  (N_USERS + M_ITEMS)
#define EMBED   64
#define N_LAYERS 3
#define BATCH   8192
#define NE      ((size_t)NNODES * EMBED)   // 9,600,000 floats

// ---------------------------------------------------------------------------
// emb_cur = emb_sum = concat(embed_user_0, embed_item_0), float4 vectorized
// ---------------------------------------------------------------------------
__global__ void init_emb(const float* __restrict__ eu, const float* __restrict__ ei,
                         float* __restrict__ cur, float* __restrict__ sum) {
    size_t t = (size_t)blockIdx.x * blockDim.x + threadIdx.x;   // float4 index
    const size_t nu4 = (size_t)N_USERS * EMBED / 4;
    const size_t n4  = NE / 4;
    if (t >= n4) return;
    float4 v = (t < nu4) ? ((const float4*)eu)[t]
                         : ((const float4*)ei)[t - nu4];
    ((float4*)cur)[t] = v;
    ((float4*)sum)[t] = v;
}

// ---------------------------------------------------------------------------
// One wave (64 lanes) per edge. lane d = feature d.
// out[src][d] += val * emb[dst][d]   (coalesced fp32 atomics)
// ---------------------------------------------------------------------------
__global__ void scatter_layer(const int* __restrict__ src, const int* __restrict__ dst,
                              const float* __restrict__ vals,
                              const float* __restrict__ emb, float* __restrict__ out,
                              int nnz) {
    int t = blockIdx.x * blockDim.x + threadIdx.x;
    int e = t >> 6;                 // wave-uniform edge index
    if (e >= nnz) return;
    int d = t & 63;
    int s  = src[e];
    int dd = dst[e];
    float v = vals[e];
    float x = v * emb[(size_t)dd * EMBED + d];
    atomicAdd(out + (size_t)s * EMBED + d, x);
}

// ---------------------------------------------------------------------------
// emb_sum += emb_next   (float4 vectorized)
// ---------------------------------------------------------------------------
__global__ void accum_sum(const float* __restrict__ nxt, float* __restrict__ sum) {
    size_t t = (size_t)blockIdx.x * blockDim.x + threadIdx.x;
    const size_t n4 = NE / 4;
    if (t >= n4) return;
    float4 a = ((const float4*)nxt)[t];
    float4 b = ((const float4*)sum)[t];
    b.x += a.x; b.y += a.y; b.z += a.z; b.w += a.w;
    ((float4*)sum)[t] = b;
}

// ---------------------------------------------------------------------------
// One wave per batch element:
//   pred_i[b] = dot(sum[u], sum[NU+i]) / 16      ( /(L+1)^2 folded in )
//   pred_j[b] = dot(sum[u], sum[NU+j]) / 16
//   reg_loss += 0.5*(|u0|^2+|i0|^2+|j0|^2)/BATCH   (atomic, slot pre-zeroed)
// ---------------------------------------------------------------------------
__global__ void predict_kernel(const int* __restrict__ user, const int* __restrict__ item_i,
                               const int* __restrict__ item_j,
                               const float* __restrict__ sum,
                               const float* __restrict__ eu0, const float* __restrict__ ei0,
                               float* __restrict__ out) {
    int t = blockIdx.x * blockDim.x + threadIdx.x;
    int b = t >> 6;
    if (b >= BATCH) return;
    int d = t & 63;
    int u  = user[b];
    int ii = item_i[b];
    int jj = item_j[b];

    float ue = sum[(size_t)u * EMBED + d];
    float ie = sum[((size_t)N_USERS + ii) * EMBED + d];
    float je = sum[((size_t)N_USERS + jj) * EMBED + d];
    float pi = ue * ie;
    float pj = ue * je;

    float u0 = eu0[(size_t)u  * EMBED + d];
    float i0 = ei0[(size_t)ii * EMBED + d];
    float j0 = ei0[(size_t)jj * EMBED + d];
    float r  = u0 * u0 + i0 * i0 + j0 * j0;

    #pragma unroll
    for (int off = 32; off > 0; off >>= 1) {
        pi += __shfl_down(pi, off);
        pj += __shfl_down(pj, off);
        r  += __shfl_down(r,  off);
    }
    if (d == 0) {
        out[b]         = pi * (1.0f / 16.0f);
        out[BATCH + b] = pj * (1.0f / 16.0f);
        atomicAdd(out + 2 * BATCH, r * (0.5f / (float)BATCH));
    }
}

// ---------------------------------------------------------------------------
extern "C" void kernel_launch(void* const* d_in, const int* in_sizes, int n_in,
                              void* d_out, int out_size, void* d_ws, size_t ws_size,
                              hipStream_t stream) {
    const int*   user      = (const int*)  d_in[0];
    const int*   item_i    = (const int*)  d_in[1];
    const int*   item_j    = (const int*)  d_in[2];
    // d_in[3] timestamp, d_in[4] split_idx: unused by the reference output
    const int*   edge_src  = (const int*)  d_in[5];
    const int*   edge_dst  = (const int*)  d_in[6];
    const float* edge_vals = (const float*)d_in[7];
    const float* eu0       = (const float*)d_in[8];
    const float* ei0       = (const float*)d_in[9];
    const int    nnz       = in_sizes[5];

    float* out = (float*)d_out;

    // workspace: 3 buffers of NE floats = 115.2 MB
    float* cur = (float*)d_ws;
    float* nxt = cur + NE;
    float* sum = nxt + NE;

    const int n4blocks = (int)((NE / 4 + 255) / 256);
    init_emb<<<n4blocks, 256, 0, stream>>>(eu0, ei0, cur, sum);

    for (int l = 0; l < N_LAYERS; ++l) {
        hipMemsetAsync(nxt, 0, NE * sizeof(float), stream);
        long total = (long)nnz * 64;
        int  blocks = (int)((total + 255) / 256);
        scatter_layer<<<blocks, 256, 0, stream>>>(edge_src, edge_dst, edge_vals,
                                                  cur, nxt, nnz);
        accum_sum<<<n4blocks, 256, 0, stream>>>(nxt, sum);
        float* tmp = cur; cur = nxt; nxt = tmp;
    }

    // zero the reg_loss slot (harness poisons d_out with 0xAA)
    hipMemsetAsync((char*)d_out + (size_t)2 * BATCH * sizeof(float), 0,
                   sizeof(float), stream);
    predict_kernel<<<(BATCH * 64 + 255) / 256, 256, 0, stream>>>(
        user, item_i, item_j, sum, eu0, ei0, out);
}

// Round 2
// 1404.528 us; speedup vs baseline: 1.3149x; 1.3149x over previous
//
#include <hip/hip_runtime.h>

#define N_USERS 100000
#define M_ITEMS 50000
#define NNODES  (N_USERS + M_ITEMS)
#define EMBED   64
#define N_LAYERS 3
#define BATCH   8192
#define NNZ_MAX 2400000

#define NU_E ((size_t)N_USERS * EMBED)   // 6,400,000 floats (user part)
#define NI_E ((size_t)M_ITEMS * EMBED)   // 3,200,000 floats (item part)
#define NE   ((size_t)NNODES * EMBED)    // 9,600,000 floats

// ---------------------------------------------------------------------------
// U = eu0 ; I_a = ei0 ; sum = concat(eu0, ei0).   float4 vectorized over NE/4.
// ---------------------------------------------------------------------------
__global__ void init_emb(const float* __restrict__ eu, const float* __restrict__ ei,
                         float* __restrict__ U, float* __restrict__ Ia,
                         float* __restrict__ sum) {
    size_t t = (size_t)blockIdx.x * blockDim.x + threadIdx.x;   // float4 index
    const size_t nu4 = NU_E / 4;
    const size_t n4  = NE / 4;
    if (t >= n4) return;
    if (t < nu4) {
        float4 v = ((const float4*)eu)[t];
        ((float4*)U)[t]   = v;
        ((float4*)sum)[t] = v;
    } else {
        float4 v = ((const float4*)ei)[t - nu4];
        ((float4*)Ia)[t - nu4] = v;
        ((float4*)sum)[t]      = v;
    }
}

// ---------------------------------------------------------------------------
// CSR build step 1: histogram of src (offs[] pre-zeroed)
// ---------------------------------------------------------------------------
__global__ void hist_kernel(const int* __restrict__ src, int* __restrict__ offs, int nnz) {
    int e = blockIdx.x * blockDim.x + threadIdx.x;
    if (e >= nnz) return;
    atomicAdd(&offs[src[e]], 1);
}

// ---------------------------------------------------------------------------
// CSR build step 2: in-place exclusive scan of offs[0..n). Single block, 1024 thr.
// ---------------------------------------------------------------------------
__global__ void scan_kernel(int* __restrict__ h, int n) {
    __shared__ int lds[1024];
    const int tid = threadIdx.x;
    const int C = (n + 1023) / 1024;
    int base = tid * C;
    int end  = min(base + C, n);
    int s = 0;
    for (int i = base; i < end; ++i) s += h[i];
    lds[tid] = s;
    __syncthreads();
    // Hillis-Steele inclusive scan over 1024 partials
    for (int off = 1; off < 1024; off <<= 1) {
        int v = (tid >= off) ? lds[tid - off] : 0;
        __syncthreads();
        lds[tid] += v;
        __syncthreads();
    }
    int run = (tid > 0) ? lds[tid - 1] : 0;   // exclusive prefix of this chunk
    for (int i = base; i < end; ++i) {
        int v = h[i];
        h[i] = run;
        run += v;
    }
}

// ---------------------------------------------------------------------------
// CSR build step 3: scatter edges into sorted position. offs[] turns from
// exclusive prefix into INCLUSIVE prefix when done (cursor trick).
// dst is pre-adjusted to index within its bipartite part (items: dst-N_USERS).
// ---------------------------------------------------------------------------
__global__ void fill_kernel(const int* __restrict__ src, const int* __restrict__ dst,
                            const float* __restrict__ vals,
                            int* __restrict__ offs, int2* __restrict__ ep, int nnz) {
    int e = blockIdx.x * blockDim.x + threadIdx.x;
    if (e >= nnz) return;
    int s = src[e];
    int d = dst[e];
    float v = vals[e];
    if (d >= N_USERS) d -= N_USERS;          // bipartite: src user <-> dst item
    int p = atomicAdd(&offs[s], 1);
    ep[p] = make_int2(d, __float_as_int(v));
}

// ---------------------------------------------------------------------------
// One wave per node in [nodeBegin, nodeBegin+nodeCount):
//   out[ln][d] = sum_{edges of node} val * other[dstIdx][d]
//   sum[node][d] += out
// After fill, offs[n] = inclusive prefix, so range = [offs[n-1], offs[n]).
// ---------------------------------------------------------------------------
__global__ void gather_part(const int* __restrict__ offs, const int2* __restrict__ ep,
                            const float* __restrict__ other,
                            float* __restrict__ outp, float* __restrict__ sum,
                            int nodeBegin, int nodeCount) {
    int t = blockIdx.x * blockDim.x + threadIdx.x;
    int ln = t >> 6;
    if (ln >= nodeCount) return;
    int d = t & 63;
    int node = nodeBegin + ln;
    int start = (node == 0) ? 0 : offs[node - 1];
    int end   = offs[node];
    float acc = 0.0f;
    for (int k = start; k < end; ++k) {
        int2 e = ep[k];
        acc = fmaf(__int_as_float(e.y), other[(size_t)e.x * EMBED + d], acc);
    }
    outp[(size_t)ln * EMBED + d] = acc;
    size_t si = (size_t)node * EMBED + d;
    sum[si] += acc;
}

// ---------------------------------------------------------------------------
// One wave per batch element (pred_i, pred_j, reg_loss). /(L+1)^2 = /16 folded.
// ---------------------------------------------------------------------------
__global__ void predict_kernel(const int* __restrict__ user, const int* __restrict__ item_i,
                               const int* __restrict__ item_j,
                               const float* __restrict__ sum,
                               const float* __restrict__ eu0, const float* __restrict__ ei0,
                               float* __restrict__ out) {
    int t = blockIdx.x * blockDim.x + threadIdx.x;
    int b = t >> 6;
    if (b >= BATCH) return;
    int d = t & 63;
    int u  = user[b];
    int ii = item_i[b];
    int jj = item_j[b];

    float ue = sum[(size_t)u * EMBED + d];
    float ie = sum[((size_t)N_USERS + ii) * EMBED + d];
    float je = sum[((size_t)N_USERS + jj) * EMBED + d];
    float pi = ue * ie;
    float pj = ue * je;

    float u0 = eu0[(size_t)u  * EMBED + d];
    float i0 = ei0[(size_t)ii * EMBED + d];
    float j0 = ei0[(size_t)jj * EMBED + d];
    float r  = u0 * u0 + i0 * i0 + j0 * j0;

    #pragma unroll
    for (int off = 32; off > 0; off >>= 1) {
        pi += __shfl_down(pi, off);
        pj += __shfl_down(pj, off);
        r  += __shfl_down(r,  off);
    }
    if (d == 0) {
        out[b]         = pi * (1.0f / 16.0f);
        out[BATCH + b] = pj * (1.0f / 16.0f);
        atomicAdd(out + 2 * BATCH, r * (0.5f / (float)BATCH));
    }
}

// ---------------------------------------------------------------------------
extern "C" void kernel_launch(void* const* d_in, const int* in_sizes, int n_in,
                              void* d_out, int out_size, void* d_ws, size_t ws_size,
                              hipStream_t stream) {
    const int*   user      = (const int*)  d_in[0];
    const int*   item_i    = (const int*)  d_in[1];
    const int*   item_j    = (const int*)  d_in[2];
    const int*   edge_src  = (const int*)  d_in[5];
    const int*   edge_dst  = (const int*)  d_in[6];
    const float* edge_vals = (const float*)d_in[7];
    const float* eu0       = (const float*)d_in[8];
    const float* ei0       = (const float*)d_in[9];
    const int    nnz       = in_sizes[5];

    float* out = (float*)d_out;

    // ---- workspace layout (109.4 MB total, fits proven >=115.2 MB budget) ----
    float* U    = (float*)d_ws;        // user part, updated in place per layer
    float* Ia   = U  + NU_E;           // item part ping
    float* Ib   = Ia + NI_E;           // item part pong
    float* sum  = Ib + NI_E;           // full running sum, [user | item] layout
    int*   offs = (int*)(sum + NE);    // NNODES+2 ints (prefix sums)
    int2*  ep   = (int2*)(offs + NNODES + 2);  // sorted {dstIdx, val} pairs

    // ---- init embeddings ----
    const int n4blocks = (int)((NE / 4 + 255) / 256);
    init_emb<<<n4blocks, 256, 0, stream>>>(eu0, ei0, U, Ia, sum);

    // ---- build CSR (once; reused by all 3 layers) ----
    hipMemsetAsync(offs, 0, (NNODES + 2) * sizeof(int), stream);
    const int eblocks = (nnz + 255) / 256;
    hist_kernel<<<eblocks, 256, 0, stream>>>(edge_src, offs, nnz);
    scan_kernel<<<1, 1024, 0, stream>>>(offs, NNODES);
    fill_kernel<<<eblocks, 256, 0, stream>>>(edge_src, edge_dst, edge_vals,
                                             offs, ep, nnz);

    // ---- 3 propagation layers (bipartite: items from users, then users from items) ----
    float* itemCur = Ia;
    float* itemNxt = Ib;
    const int iblocks = (M_ITEMS * 64) / 256;   // 12500
    const int ublocks = (N_USERS * 64) / 256;   // 25000
    for (int l = 0; l < N_LAYERS; ++l) {
        // items read old U (must run before U is overwritten)
        gather_part<<<iblocks, 256, 0, stream>>>(offs, ep, U, itemNxt, sum,
                                                 N_USERS, M_ITEMS);
        // users read old items (itemCur), overwrite U in place
        gather_part<<<ublocks, 256, 0, stream>>>(offs, ep, itemCur, U, sum,
                                                 0, N_USERS);
        float* tmp = itemCur; itemCur = itemNxt; itemNxt = tmp;
    }

    // ---- predictions + reg loss ----
    hipMemsetAsync((char*)d_out + (size_t)2 * BATCH * sizeof(float), 0,
                   sizeof(float), stream);
    predict_kernel<<<(BATCH * 64 + 255) / 256, 256, 0, stream>>>(
        user, item_i, item_j, sum, eu0, ei0, out);
}

// Round 3
// 810.465 us; speedup vs baseline: 2.2786x; 1.7330x over previous
//
#include <hip/hip_runtime.h>

#define N_USERS 100000
#define M_ITEMS 50000
#define NNODES  (N_USERS + M_ITEMS)
#define EMBED   64
#define N_LAYERS 3
#define BATCH   8192

#define NU_E ((size_t)N_USERS * EMBED)   // 6,400,000 floats (user part)
#define NI_E ((size_t)M_ITEMS * EMBED)   // 3,200,000 floats (item part)
#define NE   ((size_t)NNODES * EMBED)    // 9,600,000 floats

#define SCAN_CHUNK 1024                  // elems per scan block (256 thr x 4)
#define SCAN_NBLK  ((NNODES + SCAN_CHUNK - 1) / SCAN_CHUNK)   // 147

// ---------------------------------------------------------------------------
// U = eu0 ; I_a = ei0 ; sum = concat(eu0, ei0).   float4 vectorized.
// ---------------------------------------------------------------------------
__global__ void init_emb(const float* __restrict__ eu, const float* __restrict__ ei,
                         float* __restrict__ U, float* __restrict__ Ia,
                         float* __restrict__ sum) {
    size_t t = (size_t)blockIdx.x * blockDim.x + threadIdx.x;   // float4 index
    const size_t nu4 = NU_E / 4;
    const size_t n4  = NE / 4;
    if (t >= n4) return;
    if (t < nu4) {
        float4 v = ((const float4*)eu)[t];
        ((float4*)U)[t]   = v;
        ((float4*)sum)[t] = v;
    } else {
        float4 v = ((const float4*)ei)[t - nu4];
        ((float4*)Ia)[t - nu4] = v;
        ((float4*)sum)[t]      = v;
    }
}

// ---------------------------------------------------------------------------
// CSR build step 1: histogram of src (offs[] pre-zeroed)
// ---------------------------------------------------------------------------
__global__ void hist_kernel(const int* __restrict__ src, int* __restrict__ offs, int nnz) {
    int e = blockIdx.x * blockDim.x + threadIdx.x;
    if (e >= nnz) return;
    atomicAdd(&offs[src[e]], 1);
}

// ---------------------------------------------------------------------------
// Parallel scan phase A: each block turns its 1024-elem chunk into a
// block-local EXCLUSIVE scan and writes the chunk total to bsum[blk].
// ---------------------------------------------------------------------------
__global__ void scan_local(int* __restrict__ h, int* __restrict__ bsum, int n) {
    __shared__ int lds[256];
    const int tid = threadIdx.x;
    const int blk = blockIdx.x;
    const int base = blk * SCAN_CHUNK + tid * 4;
    int v[4];
    int s = 0;
    #pragma unroll
    for (int c = 0; c < 4; ++c) {
        v[c] = (base + c < n) ? h[base + c] : 0;
        s += v[c];
    }
    lds[tid] = s;
    __syncthreads();
    for (int off = 1; off < 256; off <<= 1) {
        int t = (tid >= off) ? lds[tid - off] : 0;
        __syncthreads();
        lds[tid] += t;
        __syncthreads();
    }
    if (tid == 255) bsum[blk] = lds[255];
    int run = (tid > 0) ? lds[tid - 1] : 0;
    #pragma unroll
    for (int c = 0; c < 4; ++c) {
        int t = v[c];
        if (base + c < n) h[base + c] = run;
        run += t;
    }
}

// ---------------------------------------------------------------------------
// Parallel scan phase B: single tiny block scans the 147 block sums (exclusive).
// ---------------------------------------------------------------------------
__global__ void scan_bsums(int* __restrict__ bsum, int nblk) {
    __shared__ int lds[256];
    const int tid = threadIdx.x;
    int v = (tid < nblk) ? bsum[tid] : 0;
    lds[tid] = v;
    __syncthreads();
    for (int off = 1; off < 256; off <<= 1) {
        int t = (tid >= off) ? lds[tid - off] : 0;
        __syncthreads();
        lds[tid] += t;
        __syncthreads();
    }
    if (tid < nblk) bsum[tid] = (tid > 0) ? lds[tid - 1] : 0;
}

// ---------------------------------------------------------------------------
// Parallel scan phase C: add block prefix back.  h becomes global exclusive scan.
// ---------------------------------------------------------------------------
__global__ void scan_add(int* __restrict__ h, const int* __restrict__ bsum, int n) {
    int i = blockIdx.x * blockDim.x + threadIdx.x;
    if (i >= n) return;
    h[i] += bsum[i / SCAN_CHUNK];
}

// ---------------------------------------------------------------------------
// CSR build step 3: scatter edges into sorted position. offs[] turns from
// exclusive prefix into INCLUSIVE prefix when done (cursor trick).
// dst pre-adjusted to bipartite-local index (items: dst - N_USERS).
// ---------------------------------------------------------------------------
__global__ void fill_kernel(const int* __restrict__ src, const int* __restrict__ dst,
                            const float* __restrict__ vals,
                            int* __restrict__ offs, int2* __restrict__ ep, int nnz) {
    int e = blockIdx.x * blockDim.x + threadIdx.x;
    if (e >= nnz) return;
    int s = src[e];
    int d = dst[e];
    float v = vals[e];
    if (d >= N_USERS) d -= N_USERS;          // bipartite: user <-> item
    int p = atomicAdd(&offs[s], 1);
    ep[p] = make_int2(d, __float_as_int(v));
}

// ---------------------------------------------------------------------------
// One wave per node, 4 edges per iteration, float4 row loads.
// lane = (sub<<4)|q : sub = edge slot 0..3, q = float4 index within 64-f row.
//   out[ln][:] = sum_{edges} val * other[dstIdx][:] ;  sum[node][:] += out
// ---------------------------------------------------------------------------
__global__ void gather_part4(const int* __restrict__ offs, const int2* __restrict__ ep,
                             const float* __restrict__ other,
                             float* __restrict__ outp, float* __restrict__ sum,
                             int nodeBegin, int nodeCount) {
    int t = blockIdx.x * blockDim.x + threadIdx.x;
    int ln = t >> 6;
    if (ln >= nodeCount) return;
    int lane = t & 63;
    int sub = lane >> 4;        // edge slot within iteration
    int q   = lane & 15;        // float4 index within the 64-float row
    int node = nodeBegin + ln;
    int start = (node == 0) ? 0 : offs[node - 1];
    int end   = offs[node];

    float4 acc = make_float4(0.f, 0.f, 0.f, 0.f);
    for (int k = start; k + sub < end; k += 4) {
        int2 e = ep[k + sub];
        float v = __int_as_float(e.y);
        float4 r = ((const float4*)other)[(size_t)e.x * 16 + q];
        acc.x = fmaf(v, r.x, acc.x);
        acc.y = fmaf(v, r.y, acc.y);
        acc.z = fmaf(v, r.z, acc.z);
        acc.w = fmaf(v, r.w, acc.w);
    }
    // reduce the 4 edge-slots (lanes differing in bits 4,5)
    acc.x += __shfl_xor(acc.x, 16); acc.y += __shfl_xor(acc.y, 16);
    acc.z += __shfl_xor(acc.z, 16); acc.w += __shfl_xor(acc.w, 16);
    acc.x += __shfl_xor(acc.x, 32); acc.y += __shfl_xor(acc.y, 32);
    acc.z += __shfl_xor(acc.z, 32); acc.w += __shfl_xor(acc.w, 32);

    if (sub == 0) {
        ((float4*)outp)[(size_t)ln * 16 + q] = acc;
        float4* sp = (float4*)(sum + (size_t)node * EMBED);
        float4 s4 = sp[q];
        s4.x += acc.x; s4.y += acc.y; s4.z += acc.z; s4.w += acc.w;
        sp[q] = s4;
    }
}

// ---------------------------------------------------------------------------
// One wave per batch element (pred_i, pred_j, reg_loss). /(L+1)^2 = /16 folded.
// ---------------------------------------------------------------------------
__global__ void predict_kernel(const int* __restrict__ user, const int* __restrict__ item_i,
                               const int* __restrict__ item_j,
                               const float* __restrict__ sum,
                               const float* __restrict__ eu0, const float* __restrict__ ei0,
                               float* __restrict__ out) {
    int t = blockIdx.x * blockDim.x + threadIdx.x;
    int b = t >> 6;
    if (b >= BATCH) return;
    int d = t & 63;
    int u  = user[b];
    int ii = item_i[b];
    int jj = item_j[b];

    float ue = sum[(size_t)u * EMBED + d];
    float ie = sum[((size_t)N_USERS + ii) * EMBED + d];
    float je = sum[((size_t)N_USERS + jj) * EMBED + d];
    float pi = ue * ie;
    float pj = ue * je;

    float u0 = eu0[(size_t)u  * EMBED + d];
    float i0 = ei0[(size_t)ii * EMBED + d];
    float j0 = ei0[(size_t)jj * EMBED + d];
    float r  = u0 * u0 + i0 * i0 + j0 * j0;

    #pragma unroll
    for (int off = 32; off > 0; off >>= 1) {
        pi += __shfl_down(pi, off);
        pj += __shfl_down(pj, off);
        r  += __shfl_down(r,  off);
    }
    if (d == 0) {
        out[b]         = pi * (1.0f / 16.0f);
        out[BATCH + b] = pj * (1.0f / 16.0f);
        atomicAdd(out + 2 * BATCH, r * (0.5f / (float)BATCH));
    }
}

// ---------------------------------------------------------------------------
extern "C" void kernel_launch(void* const* d_in, const int* in_sizes, int n_in,
                              void* d_out, int out_size, void* d_ws, size_t ws_size,
                              hipStream_t stream) {
    const int*   user      = (const int*)  d_in[0];
    const int*   item_i    = (const int*)  d_in[1];
    const int*   item_j    = (const int*)  d_in[2];
    const int*   edge_src  = (const int*)  d_in[5];
    const int*   edge_dst  = (const int*)  d_in[6];
    const float* edge_vals = (const float*)d_in[7];
    const float* eu0       = (const float*)d_in[8];
    const float* ei0       = (const float*)d_in[9];
    const int    nnz       = in_sizes[5];

    float* out = (float*)d_out;

    // ---- workspace layout (~109.5 MB) ----
    float* U    = (float*)d_ws;        // user part, updated in place per layer
    float* Ia   = U  + NU_E;           // item part ping
    float* Ib   = Ia + NI_E;           // item part pong
    float* sum  = Ib + NI_E;           // running sum, [user | item] layout
    int*   offs = (int*)(sum + NE);    // NNODES+2 ints (prefix sums)
    int2*  ep   = (int2*)(offs + NNODES + 2);   // sorted {dstIdx, val}
    int*   bsum = (int*)(ep + nnz);    // SCAN_NBLK ints

    // ---- init embeddings ----
    const int n4blocks = (int)((NE / 4 + 255) / 256);
    init_emb<<<n4blocks, 256, 0, stream>>>(eu0, ei0, U, Ia, sum);

    // ---- build CSR (once; reused by all 3 layers) ----
    hipMemsetAsync(offs, 0, (NNODES + 2) * sizeof(int), stream);
    const int eblocks = (nnz + 255) / 256;
    hist_kernel<<<eblocks, 256, 0, stream>>>(edge_src, offs, nnz);
    scan_local<<<SCAN_NBLK, 256, 0, stream>>>(offs, bsum, NNODES);
    scan_bsums<<<1, 256, 0, stream>>>(bsum, SCAN_NBLK);
    scan_add<<<(NNODES + 255) / 256, 256, 0, stream>>>(offs, bsum, NNODES);
    fill_kernel<<<eblocks, 256, 0, stream>>>(edge_src, edge_dst, edge_vals,
                                             offs, ep, nnz);

    // ---- 3 propagation layers (items from users, then users from items) ----
    float* itemCur = Ia;
    float* itemNxt = Ib;
    const int iblocks = (M_ITEMS * 64) / 256;   // 12500
    const int ublocks = (N_USERS * 64) / 256;   // 25000
    for (int l = 0; l < N_LAYERS; ++l) {
        gather_part4<<<iblocks, 256, 0, stream>>>(offs, ep, U, itemNxt, sum,
                                                  N_USERS, M_ITEMS);
        gather_part4<<<ublocks, 256, 0, stream>>>(offs, ep, itemCur, U, sum,
                                                  0, N_USERS);
        float* tmp = itemCur; itemCur = itemNxt; itemNxt = tmp;
    }

    // ---- predictions + reg loss ----
    hipMemsetAsync((char*)d_out + (size_t)2 * BATCH * sizeof(float), 0,
                   sizeof(float), stream);
    predict_kernel<<<(BATCH * 64 + 255) / 256, 256, 0, stream>>>(
        user, item_i, item_j, sum, eu0, ei0, out);
}

// Round 4
// 540.135 us; speedup vs baseline: 3.4191x; 1.5005x over previous
//
#include <hip/hip_runtime.h>

#define N_USERS 100000
#define M_ITEMS 50000
#define NNODES  (N_USERS + M_ITEMS)
#define EMBED   64
#define N_LAYERS 3
#define BATCH   8192

#define NU_E ((size_t)N_USERS * EMBED)   // 6,400,000 floats
#define NI_E ((size_t)M_ITEMS * EMBED)   // 3,200,000 floats
#define NE   ((size_t)NNODES * EMBED)    // 9,600,000 floats

#define NPB    256                        // nodes per bucket
#define NBUCK  ((NNODES + NPB - 1) / NPB) // 586
#define PBLK   256                        // partition blocks

typedef unsigned int uint;

// bf16 helpers (RNE pack, cheap unpack)
static __device__ __forceinline__ ushort f2bf(float f) {
    uint u = __float_as_uint(f);
    return (ushort)((u + 0x7fffu + ((u >> 16) & 1u)) >> 16);
}
static __device__ __forceinline__ float bf_lo(uint u) { return __uint_as_float(u << 16); }
static __device__ __forceinline__ float bf_hi(uint u) { return __uint_as_float(u & 0xffff0000u); }

// ---------------------------------------------------------------------------
// sum = concat(eu0, ei0) fp32 ; U/Ia = bf16 copies.
// ---------------------------------------------------------------------------
__global__ void init_emb(const float* __restrict__ eu, const float* __restrict__ ei,
                         ushort* __restrict__ U, ushort* __restrict__ Ia,
                         float* __restrict__ sum) {
    size_t t = (size_t)blockIdx.x * blockDim.x + threadIdx.x;   // float4 index
    const size_t nu4 = NU_E / 4;
    const size_t n4  = NE / 4;
    if (t >= n4) return;
    float4 v;
    if (t < nu4) {
        v = ((const float4*)eu)[t];
        ((ushort4*)U)[t] = make_ushort4(f2bf(v.x), f2bf(v.y), f2bf(v.z), f2bf(v.w));
    } else {
        v = ((const float4*)ei)[t - nu4];
        ((ushort4*)Ia)[t - nu4] = make_ushort4(f2bf(v.x), f2bf(v.y), f2bf(v.z), f2bf(v.w));
    }
    ((float4*)sum)[t] = v;
}

// ---------------------------------------------------------------------------
// K1: per-block LDS histogram of coarse buckets (src >> 8) -> global Hg
// ---------------------------------------------------------------------------
__global__ void hist_bucket(const int* __restrict__ src, int* __restrict__ Hg,
                            int nnz, int tile) {
    __shared__ int h[NBUCK];
    for (int i = threadIdx.x; i < NBUCK; i += 256) h[i] = 0;
    __syncthreads();
    int base = blockIdx.x * tile;
    int end  = min(base + tile, nnz);
    for (int i = base + threadIdx.x; i < end; i += 256)
        atomicAdd(&h[src[i] >> 8], 1);
    __syncthreads();
    for (int i = threadIdx.x; i < NBUCK; i += 256)
        if (h[i]) atomicAdd(&Hg[i], h[i]);
}

// ---------------------------------------------------------------------------
// K2: exclusive scan of bucket totals -> bucket_base[NBUCK+1], bucketCursor
// ---------------------------------------------------------------------------
__global__ void scan_bucket(const int* __restrict__ Hg, int* __restrict__ bucket_base,
                            int* __restrict__ bucketCursor, int nnz) {
    __shared__ int lds[1024];
    int tid = threadIdx.x;
    int v = (tid < NBUCK) ? Hg[tid] : 0;
    lds[tid] = v;
    __syncthreads();
    for (int off = 1; off < 1024; off <<= 1) {
        int t = (tid >= off) ? lds[tid - off] : 0;
        __syncthreads();
        lds[tid] += t;
        __syncthreads();
    }
    if (tid < NBUCK) {
        int ex = (tid > 0) ? lds[tid - 1] : 0;
        bucket_base[tid]   = ex;
        bucketCursor[tid]  = ex;
    }
    if (tid == NBUCK) bucket_base[tid] = nnz;
}

// ---------------------------------------------------------------------------
// K3: partition edges into coarse buckets. Per-block LDS hist, one global
// reservation atomic per (block,bucket), then LDS-cursor scatter.
// ebuf.x = (src & 255) | (dst_local << 8)   (dst_local fits 17 bits)
// ---------------------------------------------------------------------------
__global__ void partition_kernel(const int* __restrict__ src, const int* __restrict__ dst,
                                 const float* __restrict__ vals,
                                 int* __restrict__ bucketCursor, int2* __restrict__ ebuf,
                                 int nnz, int tile) {
    __shared__ int h[NBUCK];
    __shared__ int cur[NBUCK];
    for (int i = threadIdx.x; i < NBUCK; i += 256) h[i] = 0;
    __syncthreads();
    int base = blockIdx.x * tile;
    int end  = min(base + tile, nnz);
    for (int i = base + threadIdx.x; i < end; i += 256)
        atomicAdd(&h[src[i] >> 8], 1);
    __syncthreads();
    for (int i = threadIdx.x; i < NBUCK; i += 256)
        cur[i] = h[i] ? atomicAdd(&bucketCursor[i], h[i]) : 0;
    __syncthreads();
    for (int i = base + threadIdx.x; i < end; i += 256) {
        int s = src[i];
        int d = dst[i];
        float v = vals[i];
        if (d >= N_USERS) d -= N_USERS;          // bipartite-local dst index
        int p = atomicAdd(&cur[s >> 8], 1);
        ebuf[p] = make_int2((s & 255) | (d << 8), __float_as_int(v));
    }
}

// ---------------------------------------------------------------------------
// K4: one block per bucket. LDS per-node counts + scan -> final node bases.
// Writes global exclusive offs[] AND sorts edges into ep (={dst_local,val}).
// ---------------------------------------------------------------------------
__global__ void bucket_sort(const int* __restrict__ bucket_base, const int2* __restrict__ ebuf,
                            int* __restrict__ offs, int2* __restrict__ ep, int nnz) {
    __shared__ int cnt[256];
    __shared__ int sc[256];
    __shared__ int cur[256];
    int b   = blockIdx.x;
    int tid = threadIdx.x;
    int beg = bucket_base[b];
    int end = bucket_base[b + 1];
    cnt[tid] = 0;
    __syncthreads();
    for (int i = beg + tid; i < end; i += 256)
        atomicAdd(&cnt[ebuf[i].x & 255], 1);
    __syncthreads();
    sc[tid] = cnt[tid];
    __syncthreads();
    for (int off = 1; off < 256; off <<= 1) {
        int t = (tid >= off) ? sc[tid - off] : 0;
        __syncthreads();
        sc[tid] += t;
        __syncthreads();
    }
    int nodeBase = beg + ((tid > 0) ? sc[tid - 1] : 0);
    int node = b * NPB + tid;
    if (node < NNODES) offs[node] = nodeBase;
    cur[tid] = nodeBase;
    __syncthreads();
    for (int i = beg + tid; i < end; i += 256) {
        int2 e = ebuf[i];
        int p = atomicAdd(&cur[e.x & 255], 1);
        ep[p] = make_int2(e.x >> 8, e.y);
    }
    if (b == 0 && tid == 0) offs[NNODES] = nnz;
}

// ---------------------------------------------------------------------------
// Gather: one wave per node, 8 edges/iter, bf16x8 (16 B) loads.
// lane = (sub<<3)|q : sub = edge slot 0..7, q = 8-bf16 chunk 0..7.
// Writes bf16 next-layer row and updates fp32 running sum.
// ---------------------------------------------------------------------------
__global__ void gather_bf8(const int* __restrict__ offs, const int2* __restrict__ ep,
                           const ushort* __restrict__ other,
                           ushort* __restrict__ outp, float* __restrict__ sum,
                           int nodeBegin, int nodeCount) {
    int t = blockIdx.x * blockDim.x + threadIdx.x;
    int ln = t >> 6;
    if (ln >= nodeCount) return;
    int lane = t & 63;
    int sub = lane >> 3;
    int q   = lane & 7;
    int node = nodeBegin + ln;
    int start = offs[node];
    int end   = offs[node + 1];

    float a0=0.f,a1=0.f,a2=0.f,a3=0.f,a4=0.f,a5=0.f,a6=0.f,a7=0.f;
    for (int k = start; k + sub < end; k += 8) {
        int2 e = ep[k + sub];
        float v = __int_as_float(e.y);
        uint4 r = ((const uint4*)other)[(size_t)e.x * 8 + q];   // 8 bf16
        a0 = fmaf(v, bf_lo(r.x), a0);  a1 = fmaf(v, bf_hi(r.x), a1);
        a2 = fmaf(v, bf_lo(r.y), a2);  a3 = fmaf(v, bf_hi(r.y), a3);
        a4 = fmaf(v, bf_lo(r.z), a4);  a5 = fmaf(v, bf_hi(r.z), a5);
        a6 = fmaf(v, bf_lo(r.w), a6);  a7 = fmaf(v, bf_hi(r.w), a7);
    }
    // reduce across the 8 edge-slots (lane bits 3,4,5)
    #pragma unroll
    for (int off = 8; off <= 32; off <<= 1) {
        a0 += __shfl_xor(a0, off); a1 += __shfl_xor(a1, off);
        a2 += __shfl_xor(a2, off); a3 += __shfl_xor(a3, off);
        a4 += __shfl_xor(a4, off); a5 += __shfl_xor(a5, off);
        a6 += __shfl_xor(a6, off); a7 += __shfl_xor(a7, off);
    }
    if (sub == 0) {   // lanes 0..7, lane == q
        uint4 o;
        o.x = (uint)f2bf(a0) | ((uint)f2bf(a1) << 16);
        o.y = (uint)f2bf(a2) | ((uint)f2bf(a3) << 16);
        o.z = (uint)f2bf(a4) | ((uint)f2bf(a5) << 16);
        o.w = (uint)f2bf(a6) | ((uint)f2bf(a7) << 16);
        ((uint4*)outp)[(size_t)ln * 8 + q] = o;

        float4* sp = (float4*)(sum + (size_t)node * EMBED) + 2 * q;
        float4 s0 = sp[0], s1 = sp[1];
        s0.x += a0; s0.y += a1; s0.z += a2; s0.w += a3;
        s1.x += a4; s1.y += a5; s1.z += a6; s1.w += a7;
        sp[0] = s0; sp[1] = s1;
    }
}

// ---------------------------------------------------------------------------
// One wave per batch element (pred_i, pred_j, reg_loss). /(L+1)^2 = /16 folded.
// ---------------------------------------------------------------------------
__global__ void predict_kernel(const int* __restrict__ user, const int* __restrict__ item_i,
                               const int* __restrict__ item_j,
                               const float* __restrict__ sum,
                               const float* __restrict__ eu0, const float* __restrict__ ei0,
                               float* __restrict__ out) {
    int t = blockIdx.x * blockDim.x + threadIdx.x;
    int b = t >> 6;
    if (b >= BATCH) return;
    int d = t & 63;
    int u  = user[b];
    int ii = item_i[b];
    int jj = item_j[b];

    float ue = sum[(size_t)u * EMBED + d];
    float ie = sum[((size_t)N_USERS + ii) * EMBED + d];
    float je = sum[((size_t)N_USERS + jj) * EMBED + d];
    float pi = ue * ie;
    float pj = ue * je;

    float u0 = eu0[(size_t)u  * EMBED + d];
    float i0 = ei0[(size_t)ii * EMBED + d];
    float j0 = ei0[(size_t)jj * EMBED + d];
    float r  = u0 * u0 + i0 * i0 + j0 * j0;

    #pragma unroll
    for (int off = 32; off > 0; off >>= 1) {
        pi += __shfl_down(pi, off);
        pj += __shfl_down(pj, off);
        r  += __shfl_down(r,  off);
    }
    if (d == 0) {
        out[b]         = pi * (1.0f / 16.0f);
        out[BATCH + b] = pj * (1.0f / 16.0f);
        atomicAdd(out + 2 * BATCH, r * (0.5f / (float)BATCH));
    }
}

// ---------------------------------------------------------------------------
extern "C" void kernel_launch(void* const* d_in, const int* in_sizes, int n_in,
                              void* d_out, int out_size, void* d_ws, size_t ws_size,
                              hipStream_t stream) {
    const int*   user      = (const int*)  d_in[0];
    const int*   item_i    = (const int*)  d_in[1];
    const int*   item_j    = (const int*)  d_in[2];
    const int*   edge_src  = (const int*)  d_in[5];
    const int*   edge_dst  = (const int*)  d_in[6];
    const float* edge_vals = (const float*)d_in[7];
    const float* eu0       = (const float*)d_in[8];
    const float* ei0       = (const float*)d_in[9];
    const int    nnz       = in_sizes[5];

    float* out = (float*)d_out;

    // ---- workspace layout (~84 MB; ebuf aliases the bf16 buffers) ----
    float*  sum  = (float*)d_ws;                 // 38.4 MB fp32
    ushort* U    = (ushort*)(sum + NE);          // 12.8 MB bf16
    ushort* Ia   = U  + NU_E;                    //  6.4 MB bf16
    ushort* Ib   = Ia + NI_E;                    //  6.4 MB bf16
    int2*   ep   = (int2*)(Ib + NI_E);           // 19.2 MB sorted {dst,val}
    int*    offs = (int*)(ep + nnz);             // NNODES+1 ints
    int*    Hg   = offs + NNODES + 2;            // NBUCK
    int*    bucket_base = Hg + NBUCK;            // NBUCK+1
    int*    bucketCursor = bucket_base + NBUCK + 2;
    int2*   ebuf = (int2*)U;                     // 19.2 MB, dead after bucket_sort

    // ---- build CSR (before init_emb: ebuf aliases U/Ia/Ib) ----
    const int tile = (nnz + PBLK - 1) / PBLK;
    hipMemsetAsync(Hg, 0, NBUCK * sizeof(int), stream);
    hist_bucket<<<PBLK, 256, 0, stream>>>(edge_src, Hg, nnz, tile);
    scan_bucket<<<1, 1024, 0, stream>>>(Hg, bucket_base, bucketCursor, nnz);
    partition_kernel<<<PBLK, 256, 0, stream>>>(edge_src, edge_dst, edge_vals,
                                               bucketCursor, ebuf, nnz, tile);
    bucket_sort<<<NBUCK, 256, 0, stream>>>(bucket_base, ebuf, offs, ep, nnz);

    // ---- init embeddings (overwrites ebuf region) ----
    const int n4blocks = (int)((NE / 4 + 255) / 256);
    init_emb<<<n4blocks, 256, 0, stream>>>(eu0, ei0, U, Ia, sum);

    // ---- 3 propagation layers (items from users, then users from items) ----
    ushort* itemCur = Ia;
    ushort* itemNxt = Ib;
    const int iblocks = (M_ITEMS * 64) / 256;   // 12500
    const int ublocks = (N_USERS * 64) / 256;   // 25000
    for (int l = 0; l < N_LAYERS; ++l) {
        gather_bf8<<<iblocks, 256, 0, stream>>>(offs, ep, U, itemNxt, sum,
                                                N_USERS, M_ITEMS);
        gather_bf8<<<ublocks, 256, 0, stream>>>(offs, ep, itemCur, U, sum,
                                                0, N_USERS);
        ushort* tmp = itemCur; itemCur = itemNxt; itemNxt = tmp;
    }

    // ---- predictions + reg loss ----
    hipMemsetAsync((char*)d_out + (size_t)2 * BATCH * sizeof(float), 0,
                   sizeof(float), stream);
    predict_kernel<<<(BATCH * 64 + 255) / 256, 256, 0, stream>>>(
        user, item_i, item_j, sum, eu0, ei0, out);
}

// Round 5
// 430.498 us; speedup vs baseline: 4.2898x; 1.2547x over previous
//
#include <hip/hip_runtime.h>

#define N_USERS 100000
#define M_ITEMS 50000
#define NNODES  (N_USERS + M_ITEMS)
#define EMBED   64
#define N_LAYERS 3
#define BATCH   8192

#define NU_E ((size_t)N_USERS * EMBED)   // 6,400,000 floats
#define NI_E ((size_t)M_ITEMS * EMBED)   // 3,200,000 floats
#define NE   ((size_t)NNODES * EMBED)    // 9,600,000 floats

#define NPB    256                        // nodes per bucket
#define NBUCK  ((NNODES + NPB - 1) / NPB) // 586
#define PBLK   256                        // partition blocks
#define PRED_BLOCKS ((BATCH * 64) / 256)  // 2048

typedef unsigned int uint;

// bf16 helpers (RNE pack, cheap unpack)
static __device__ __forceinline__ ushort f2bf(float f) {
    uint u = __float_as_uint(f);
    return (ushort)((u + 0x7fffu + ((u >> 16) & 1u)) >> 16);
}
static __device__ __forceinline__ float bf_lo(uint u) { return __uint_as_float(u << 16); }
static __device__ __forceinline__ float bf_hi(uint u) { return __uint_as_float(u & 0xffff0000u); }

// ---------------------------------------------------------------------------
// sum = concat(eu0, ei0) fp32 ; U/Ia = bf16 copies.
// ---------------------------------------------------------------------------
__global__ void init_emb(const float* __restrict__ eu, const float* __restrict__ ei,
                         ushort* __restrict__ U, ushort* __restrict__ Ia,
                         float* __restrict__ sum) {
    size_t t = (size_t)blockIdx.x * blockDim.x + threadIdx.x;   // float4 index
    const size_t nu4 = NU_E / 4;
    const size_t n4  = NE / 4;
    if (t >= n4) return;
    float4 v;
    if (t < nu4) {
        v = ((const float4*)eu)[t];
        ((ushort4*)U)[t] = make_ushort4(f2bf(v.x), f2bf(v.y), f2bf(v.z), f2bf(v.w));
    } else {
        v = ((const float4*)ei)[t - nu4];
        ((ushort4*)Ia)[t - nu4] = make_ushort4(f2bf(v.x), f2bf(v.y), f2bf(v.z), f2bf(v.w));
    }
    ((float4*)sum)[t] = v;
}

// ---------------------------------------------------------------------------
// K1: per-block LDS histogram of coarse buckets (src >> 8) -> global Hg
// ---------------------------------------------------------------------------
__global__ void hist_bucket(const int* __restrict__ src, int* __restrict__ Hg,
                            int nnz, int tile) {
    __shared__ int h[NBUCK];
    for (int i = threadIdx.x; i < NBUCK; i += 256) h[i] = 0;
    __syncthreads();
    int base = blockIdx.x * tile;
    int end  = min(base + tile, nnz);
    for (int i = base + threadIdx.x; i < end; i += 256)
        atomicAdd(&h[src[i] >> 8], 1);
    __syncthreads();
    for (int i = threadIdx.x; i < NBUCK; i += 256)
        if (h[i]) atomicAdd(&Hg[i], h[i]);
}

// ---------------------------------------------------------------------------
// K2: exclusive scan of bucket totals -> bucket_base[NBUCK+1], bucketCursor
// ---------------------------------------------------------------------------
__global__ void scan_bucket(const int* __restrict__ Hg, int* __restrict__ bucket_base,
                            int* __restrict__ bucketCursor, int nnz) {
    __shared__ int lds[1024];
    int tid = threadIdx.x;
    int v = (tid < NBUCK) ? Hg[tid] : 0;
    lds[tid] = v;
    __syncthreads();
    for (int off = 1; off < 1024; off <<= 1) {
        int t = (tid >= off) ? lds[tid - off] : 0;
        __syncthreads();
        lds[tid] += t;
        __syncthreads();
    }
    if (tid < NBUCK) {
        int ex = (tid > 0) ? lds[tid - 1] : 0;
        bucket_base[tid]   = ex;
        bucketCursor[tid]  = ex;
    }
    if (tid == NBUCK) bucket_base[tid] = nnz;
}

// ---------------------------------------------------------------------------
// K3: partition edges into coarse buckets (LDS cursors, contiguous runs out).
// ebuf.x = (src & 255) | (dst_local << 8)
// ---------------------------------------------------------------------------
__global__ void partition_kernel(const int* __restrict__ src, const int* __restrict__ dst,
                                 const float* __restrict__ vals,
                                 int* __restrict__ bucketCursor, int2* __restrict__ ebuf,
                                 int nnz, int tile) {
    __shared__ int h[NBUCK];
    __shared__ int cur[NBUCK];
    for (int i = threadIdx.x; i < NBUCK; i += 256) h[i] = 0;
    __syncthreads();
    int base = blockIdx.x * tile;
    int end  = min(base + tile, nnz);
    for (int i = base + threadIdx.x; i < end; i += 256)
        atomicAdd(&h[src[i] >> 8], 1);
    __syncthreads();
    for (int i = threadIdx.x; i < NBUCK; i += 256)
        cur[i] = h[i] ? atomicAdd(&bucketCursor[i], h[i]) : 0;
    __syncthreads();
    for (int i = base + threadIdx.x; i < end; i += 256) {
        int s = src[i];
        int d = dst[i];
        float v = vals[i];
        if (d >= N_USERS) d -= N_USERS;          // bipartite-local dst index
        int p = atomicAdd(&cur[s >> 8], 1);
        ebuf[p] = make_int2((s & 255) | (d << 8), __float_as_int(v));
    }
}

// ---------------------------------------------------------------------------
// K4: one block per bucket: LDS counts+scan -> offs[], sort edges into ep.
// ---------------------------------------------------------------------------
__global__ void bucket_sort(const int* __restrict__ bucket_base, const int2* __restrict__ ebuf,
                            int* __restrict__ offs, int2* __restrict__ ep, int nnz) {
    __shared__ int cnt[256];
    __shared__ int sc[256];
    __shared__ int cur[256];
    int b   = blockIdx.x;
    int tid = threadIdx.x;
    int beg = bucket_base[b];
    int end = bucket_base[b + 1];
    cnt[tid] = 0;
    __syncthreads();
    for (int i = beg + tid; i < end; i += 256)
        atomicAdd(&cnt[ebuf[i].x & 255], 1);
    __syncthreads();
    sc[tid] = cnt[tid];
    __syncthreads();
    for (int off = 1; off < 256; off <<= 1) {
        int t = (tid >= off) ? sc[tid - off] : 0;
        __syncthreads();
        sc[tid] += t;
        __syncthreads();
    }
    int nodeBase = beg + ((tid > 0) ? sc[tid - 1] : 0);
    int node = b * NPB + tid;
    if (node < NNODES) offs[node] = nodeBase;
    cur[tid] = nodeBase;
    __syncthreads();
    for (int i = beg + tid; i < end; i += 256) {
        int2 e = ebuf[i];
        int p = atomicAdd(&cur[e.x & 255], 1);
        ep[p] = make_int2(e.x >> 8, e.y);
    }
    if (b == 0 && tid == 0) offs[NNODES] = nnz;
}

// ---------------------------------------------------------------------------
// Gather: 8 nodes per wave, 8 lanes per node. lane = g*8+q.
// Lane (g,q) owns 16 B (8 bf16) chunk q of node g's row: no cross-lane
// reduction, full-wave coalesced stores. Loop = wave-max degree, 2x unrolled.
// ---------------------------------------------------------------------------
__global__ void gather_g8(const int* __restrict__ offs, const int2* __restrict__ ep,
                          const ushort* __restrict__ other,
                          ushort* __restrict__ outp, float* __restrict__ sum,
                          int nodeBegin, int nodeCount, int writeOut) {
    int t = blockIdx.x * blockDim.x + threadIdx.x;
    int wave = t >> 6;
    int lane = t & 63;
    int g = lane >> 3;              // node slot within wave
    int q = lane & 7;               // uint4 chunk within row
    int ln = wave * 8 + g;
    bool valid = ln < nodeCount;
    int node = nodeBegin + (valid ? ln : 0);
    int start = valid ? offs[node] : 0;
    int deg   = valid ? offs[node + 1] - start : 0;

    // wave-uniform max degree (butterfly over the g bits 3..5)
    int md = deg;
    #pragma unroll
    for (int off = 8; off <= 32; off <<= 1) md = max(md, __shfl_xor(md, off));

    float a0=0.f,a1=0.f,a2=0.f,a3=0.f,a4=0.f,a5=0.f,a6=0.f,a7=0.f;
    for (int k = 0; k < md; k += 2) {
        bool p0 = k < deg, p1 = k + 1 < deg;
        int2 e0 = p0 ? ep[start + k]     : make_int2(0, 0);
        int2 e1 = p1 ? ep[start + k + 1] : make_int2(0, 0);
        if (p0) {
            float v = __int_as_float(e0.y);
            uint4 r = ((const uint4*)other)[(size_t)e0.x * 8 + q];
            a0 = fmaf(v, bf_lo(r.x), a0);  a1 = fmaf(v, bf_hi(r.x), a1);
            a2 = fmaf(v, bf_lo(r.y), a2);  a3 = fmaf(v, bf_hi(r.y), a3);
            a4 = fmaf(v, bf_lo(r.z), a4);  a5 = fmaf(v, bf_hi(r.z), a5);
            a6 = fmaf(v, bf_lo(r.w), a6);  a7 = fmaf(v, bf_hi(r.w), a7);
        }
        if (p1) {
            float v = __int_as_float(e1.y);
            uint4 r = ((const uint4*)other)[(size_t)e1.x * 8 + q];
            a0 = fmaf(v, bf_lo(r.x), a0);  a1 = fmaf(v, bf_hi(r.x), a1);
            a2 = fmaf(v, bf_lo(r.y), a2);  a3 = fmaf(v, bf_hi(r.y), a3);
            a4 = fmaf(v, bf_lo(r.z), a4);  a5 = fmaf(v, bf_hi(r.z), a5);
            a6 = fmaf(v, bf_lo(r.w), a6);  a7 = fmaf(v, bf_hi(r.w), a7);
        }
    }

    if (!valid) return;
    if (writeOut) {
        uint4 o;
        o.x = (uint)f2bf(a0) | ((uint)f2bf(a1) << 16);
        o.y = (uint)f2bf(a2) | ((uint)f2bf(a3) << 16);
        o.z = (uint)f2bf(a4) | ((uint)f2bf(a5) << 16);
        o.w = (uint)f2bf(a6) | ((uint)f2bf(a7) << 16);
        ((uint4*)outp)[(size_t)ln * 8 + q] = o;
    }
    float4* sp = (float4*)(sum + (size_t)node * EMBED) + 2 * q;
    float4 s0 = sp[0], s1 = sp[1];
    s0.x += a0; s0.y += a1; s0.z += a2; s0.w += a3;
    s1.x += a4; s1.y += a5; s1.z += a6; s1.w += a7;
    sp[0] = s0; sp[1] = s1;
}

// ---------------------------------------------------------------------------
// One wave per batch element; reg-loss partials per block (NO global atomic).
// ---------------------------------------------------------------------------
__global__ void predict_kernel(const int* __restrict__ user, const int* __restrict__ item_i,
                               const int* __restrict__ item_j,
                               const float* __restrict__ sum,
                               const float* __restrict__ eu0, const float* __restrict__ ei0,
                               float* __restrict__ out, float* __restrict__ rbuf) {
    __shared__ float rpart[4];
    int t = blockIdx.x * blockDim.x + threadIdx.x;
    int b = t >> 6;
    int d = t & 63;
    int wv = threadIdx.x >> 6;
    float pi = 0.f, pj = 0.f, r = 0.f;
    if (b < BATCH) {
        int u  = user[b];
        int ii = item_i[b];
        int jj = item_j[b];
        float ue = sum[(size_t)u * EMBED + d];
        float ie = sum[((size_t)N_USERS + ii) * EMBED + d];
        float je = sum[((size_t)N_USERS + jj) * EMBED + d];
        pi = ue * ie;
        pj = ue * je;
        float u0 = eu0[(size_t)u  * EMBED + d];
        float i0 = ei0[(size_t)ii * EMBED + d];
        float j0 = ei0[(size_t)jj * EMBED + d];
        r = u0 * u0 + i0 * i0 + j0 * j0;
    }
    #pragma unroll
    for (int off = 32; off > 0; off >>= 1) {
        pi += __shfl_down(pi, off);
        pj += __shfl_down(pj, off);
        r  += __shfl_down(r,  off);
    }
    if (d == 0 && b < BATCH) {
        out[b]         = pi * (1.0f / 16.0f);
        out[BATCH + b] = pj * (1.0f / 16.0f);
        rpart[wv] = r;
    }
    __syncthreads();
    if (threadIdx.x == 0)
        rbuf[blockIdx.x] = rpart[0] + rpart[1] + rpart[2] + rpart[3];
}

// ---------------------------------------------------------------------------
// Reduce the 2048 block partials -> out[2*BATCH]
// ---------------------------------------------------------------------------
__global__ void finalize_reg(const float* __restrict__ rbuf, float* __restrict__ out) {
    __shared__ float lds[4];
    int tid = threadIdx.x;
    float s = 0.f;
    for (int i = tid; i < PRED_BLOCKS; i += 256) s += rbuf[i];
    #pragma unroll
    for (int off = 32; off > 0; off >>= 1) s += __shfl_down(s, off);
    if ((tid & 63) == 0) lds[tid >> 6] = s;
    __syncthreads();
    if (tid == 0)
        out[2 * BATCH] = (lds[0] + lds[1] + lds[2] + lds[3]) * (0.5f / (float)BATCH);
}

// ---------------------------------------------------------------------------
extern "C" void kernel_launch(void* const* d_in, const int* in_sizes, int n_in,
                              void* d_out, int out_size, void* d_ws, size_t ws_size,
                              hipStream_t stream) {
    const int*   user      = (const int*)  d_in[0];
    const int*   item_i    = (const int*)  d_in[1];
    const int*   item_j    = (const int*)  d_in[2];
    const int*   edge_src  = (const int*)  d_in[5];
    const int*   edge_dst  = (const int*)  d_in[6];
    const float* edge_vals = (const float*)d_in[7];
    const float* eu0       = (const float*)d_in[8];
    const float* ei0       = (const float*)d_in[9];
    const int    nnz       = in_sizes[5];

    float* out = (float*)d_out;

    // ---- workspace layout (~84 MB; ebuf aliases the bf16 buffers) ----
    float*  sum  = (float*)d_ws;                 // 38.4 MB fp32
    ushort* U    = (ushort*)(sum + NE);          // 12.8 MB bf16
    ushort* Ia   = U  + NU_E;                    //  6.4 MB bf16
    ushort* Ib   = Ia + NI_E;                    //  6.4 MB bf16
    int2*   ep   = (int2*)(Ib + NI_E);           // 19.2 MB sorted {dst,val}
    int*    offs = (int*)(ep + nnz);             // NNODES+1 ints
    int*    Hg   = offs + NNODES + 2;            // NBUCK
    int*    bucket_base = Hg + NBUCK;            // NBUCK+1
    int*    bucketCursor = bucket_base + NBUCK + 2;
    float*  rbuf = (float*)(bucketCursor + NBUCK + 2);   // PRED_BLOCKS floats
    int2*   ebuf = (int2*)U;                     // 19.2 MB, dead after bucket_sort

    // ---- build CSR (before init_emb: ebuf aliases U/Ia/Ib) ----
    const int tile = (nnz + PBLK - 1) / PBLK;
    hipMemsetAsync(Hg, 0, NBUCK * sizeof(int), stream);
    hist_bucket<<<PBLK, 256, 0, stream>>>(edge_src, Hg, nnz, tile);
    scan_bucket<<<1, 1024, 0, stream>>>(Hg, bucket_base, bucketCursor, nnz);
    partition_kernel<<<PBLK, 256, 0, stream>>>(edge_src, edge_dst, edge_vals,
                                               bucketCursor, ebuf, nnz, tile);
    bucket_sort<<<NBUCK, 256, 0, stream>>>(bucket_base, ebuf, offs, ep, nnz);

    // ---- init embeddings (overwrites ebuf region) ----
    const int n4blocks = (int)((NE / 4 + 255) / 256);
    init_emb<<<n4blocks, 256, 0, stream>>>(eu0, ei0, U, Ia, sum);

    // ---- 3 propagation layers (items from users, then users from items) ----
    ushort* itemCur = Ia;
    ushort* itemNxt = Ib;
    const int iwaves = (M_ITEMS + 7) / 8;       // 6250 waves
    const int uwaves = (N_USERS + 7) / 8;       // 12500 waves
    const int iblocks = (iwaves * 64 + 255) / 256;
    const int ublocks = (uwaves * 64 + 255) / 256;
    for (int l = 0; l < N_LAYERS; ++l) {
        int last = (l == N_LAYERS - 1);
        gather_g8<<<iblocks, 256, 0, stream>>>(offs, ep, U, itemNxt, sum,
                                               N_USERS, M_ITEMS, !last);
        gather_g8<<<ublocks, 256, 0, stream>>>(offs, ep, itemCur, U, sum,
                                               0, N_USERS, !last);
        ushort* tmp = itemCur; itemCur = itemNxt; itemNxt = tmp;
    }

    // ---- predictions + reg loss (no same-address atomics) ----
    predict_kernel<<<PRED_BLOCKS, 256, 0, stream>>>(
        user, item_i, item_j, sum, eu0, ei0, out, rbuf);
    finalize_reg<<<1, 256, 0, stream>>>(rbuf, out);
}